// Round 9
// baseline (263.393 us; speedup 1.0000x reference)
//
#include <hip/hip_runtime.h>

// MHA: fp32 in, fp32 out. B=2, S=2048, D=1024, H=16, dk=64. bf16 MFMA internals.
// ws 16MB: Kp[0,8) Vt[8,16) -> later O32[0,16).
// d_out 16MB: Qp/ctx[0,8), WqT/WkT/WvT/WoT bf16 [8,16).
// GEMM: round-0 structure (reg-staged prefetch distance 1, 2 barriers/K-step)
//       — measured best of 4 variants tried; do not restructure without A/B.
// attn v5 = v4 + XCD-aware block remap: all 16 q-tile blocks of one (b,h)
//       land on one XCD (bh = (flat&7) + 8*(slot>>4)), so K/V tiles are
//       fetched into that XCD's L2 once and L2-hit by the other 15 blocks.
//       Rationale: round-8 FETCH 73.9MB vs 24MB unique = 3x XCD-duplicated
//       overfetch; per-iter wall 10.8k cyc vs 2.6k busy = fetch-latency bound.
// attn core (from v4, verified): 4 waves x 32q x 128-key tiles, 32x32 MFMA,
//       swapped QK^T, in-register P via cvt_pk+permlane32_swap, mask as f32
//       bias in LDS, row-sums via MFMA(P, ones), XOR LDS (0 conflicts).

typedef unsigned short u16;
typedef unsigned int u32;
typedef __attribute__((ext_vector_type(8))) short bf16x8;    // MFMA A/B frag (4 VGPR)
typedef __attribute__((ext_vector_type(4))) float f32x4;     // 16x16 C/D frag
typedef __attribute__((ext_vector_type(16))) float f32x16;   // 32x32 C/D frag
typedef __attribute__((ext_vector_type(2))) int i32x2;

static __device__ __forceinline__ u16 f2bf(float x) {        // round-half-up
  union { float f; u32 i; } v; v.f = x;
  return (u16)((v.i + 0x8000u) >> 16);
}

static __device__ __forceinline__ u32 cvtpk(float lo, float hi) {
  u32 r;
  asm("v_cvt_pk_bf16_f32 %0, %1, %2" : "=v"(r) : "v"(lo), "v"(hi));
  return r;
}

#define MFMA_B16(a, b, c) __builtin_amdgcn_mfma_f32_16x16x32_bf16((a), (b), (c), 0, 0, 0)
#define MFMA32_B16(a, b, c) __builtin_amdgcn_mfma_f32_32x32x16_bf16((a), (b), (c), 0, 0, 0)

// ---------------- prep: W fp32[K][N] -> Wt bf16[N][K], 4 weights -------------
__global__ __launch_bounds__(256) void prep_w(
    const float* __restrict__ w0, const float* __restrict__ w1,
    const float* __restrict__ w2, const float* __restrict__ w3,
    u16* __restrict__ t0, u16* __restrict__ t1,
    u16* __restrict__ t2, u16* __restrict__ t3) {
  __shared__ u16 tile[64 * 68];
  const float* W; u16* T;
  switch (blockIdx.z) {
    case 0: W = w0; T = t0; break;
    case 1: W = w1; T = t1; break;
    case 2: W = w2; T = t2; break;
    default: W = w3; T = t3; break;
  }
  const int t = threadIdx.x;
  const int k0 = blockIdx.x * 64, n0 = blockIdx.y * 64;
#pragma unroll
  for (int it = 0; it < 4; ++it) {
    int idx = it * 256 + t;
    int r = idx >> 4, c4 = idx & 15;
    float4 v = *(const float4*)&W[(size_t)(k0 + r) * 1024 + n0 + c4 * 4];
    tile[r * 68 + c4 * 4 + 0] = f2bf(v.x);
    tile[r * 68 + c4 * 4 + 1] = f2bf(v.y);
    tile[r * 68 + c4 * 4 + 2] = f2bf(v.z);
    tile[r * 68 + c4 * 4 + 3] = f2bf(v.w);
  }
  __syncthreads();
#pragma unroll
  for (int it = 0; it < 2; ++it) {
    int idx = it * 256 + t;
    int n = idx >> 3, kc = idx & 7;
    bf16x8 pk;
#pragma unroll
    for (int j = 0; j < 8; ++j) pk[j] = (short)tile[(kc * 8 + j) * 68 + n];
    *(bf16x8*)&T[(size_t)(n0 + n) * 1024 + k0 + kc * 8] = pk;
  }
}

// ---------------- GEMM, tile (MT*32)x128, BK=32, reg-staged prefetch ---------
template <int MT, int AMODE, int OMODE>
__global__ __launch_bounds__(256) void gemm_bias(
    const void* a0v, const void* a1v, const void* a2v,
    const u16* __restrict__ Wt,
    const float* b0, const float* b1, const float* b2,
    void* o0, void* o1, void* o2) {
  __shared__ __align__(16) u16 As[MT * 32 * 32];
  __shared__ __align__(16) u16 Bs[128 * 32];
  const int t = threadIdx.x, wave = t >> 6, lane = t & 63;
  const int l15 = lane & 15, quad = lane >> 4;
  const int m0 = blockIdx.x * (MT * 32);
  const int n0 = blockIdx.y * 128;
  const int rg = (OMODE == 3) ? (n0 >> 10) : 0;
  const void* Av = (rg == 0) ? a0v : (rg == 1 ? a1v : a2v);
  const float* bp = (rg == 0) ? b0 : (rg == 1 ? b1 : b2);
  const int nb = (OMODE == 3) ? (n0 & 1023) : n0;
  const int wr = (wave >> 1) * (MT * 16), wc = (wave & 1) * 64;

  const f32x4 fz = {0.f, 0.f, 0.f, 0.f};
  f32x4 acc[MT][4];
#pragma unroll
  for (int mt = 0; mt < MT; ++mt)
#pragma unroll
    for (int nt = 0; nt < 4; ++nt) acc[mt][nt] = fz;

  float4 pa[MT / 2][2]; bf16x8 pab[MT / 2]; bf16x8 pb[2];
#pragma unroll
  for (int s = 0; s < MT / 2; ++s) {
    int idx = s * 256 + t, row = idx >> 2, seg = idx & 3;
    if (AMODE == 1) {
      const float* ap = (const float*)Av + (size_t)(m0 + row) * 1024 + seg * 8;
      pa[s][0] = *(const float4*)ap; pa[s][1] = *(const float4*)(ap + 4);
    } else {
      pab[s] = *(const bf16x8*)((const u16*)Av + (size_t)(m0 + row) * 1024 + seg * 8);
    }
  }
#pragma unroll
  for (int s = 0; s < 2; ++s) {
    int idx = s * 256 + t, row = idx >> 2, seg = idx & 3;
    pb[s] = *(const bf16x8*)&Wt[(size_t)(n0 + row) * 1024 + seg * 8];
  }

  for (int kb = 0; kb < 1024; kb += 32) {
    __syncthreads();
#pragma unroll
    for (int s = 0; s < MT / 2; ++s) {
      int idx = s * 256 + t, row = idx >> 2, seg = idx & 3;
      bf16x8 pk;
      if (AMODE == 1) {
        pk[0] = (short)f2bf(pa[s][0].x); pk[1] = (short)f2bf(pa[s][0].y);
        pk[2] = (short)f2bf(pa[s][0].z); pk[3] = (short)f2bf(pa[s][0].w);
        pk[4] = (short)f2bf(pa[s][1].x); pk[5] = (short)f2bf(pa[s][1].y);
        pk[6] = (short)f2bf(pa[s][1].z); pk[7] = (short)f2bf(pa[s][1].w);
      } else pk = pab[s];
      *(bf16x8*)&As[row * 32 + seg * 8] = pk;
    }
#pragma unroll
    for (int s = 0; s < 2; ++s) {
      int idx = s * 256 + t, row = idx >> 2, seg = idx & 3;
      *(bf16x8*)&Bs[row * 32 + seg * 8] = pb[s];
    }
    __syncthreads();
    const int kn = (kb + 32) & 1023;
#pragma unroll
    for (int s = 0; s < MT / 2; ++s) {
      int idx = s * 256 + t, row = idx >> 2, seg = idx & 3;
      if (AMODE == 1) {
        const float* ap = (const float*)Av + (size_t)(m0 + row) * 1024 + kn + seg * 8;
        pa[s][0] = *(const float4*)ap; pa[s][1] = *(const float4*)(ap + 4);
      } else {
        pab[s] = *(const bf16x8*)((const u16*)Av + (size_t)(m0 + row) * 1024 + kn + seg * 8);
      }
    }
#pragma unroll
    for (int s = 0; s < 2; ++s) {
      int idx = s * 256 + t, row = idx >> 2, seg = idx & 3;
      pb[s] = *(const bf16x8*)&Wt[(size_t)(n0 + row) * 1024 + kn + seg * 8];
    }
    bf16x8 a[MT], bfr[4];
#pragma unroll
    for (int mt = 0; mt < MT; ++mt)
      a[mt] = *(const bf16x8*)&As[(wr + mt * 16 + l15) * 32 + quad * 8];
#pragma unroll
    for (int nt = 0; nt < 4; ++nt)
      bfr[nt] = *(const bf16x8*)&Bs[(wc + nt * 16 + l15) * 32 + quad * 8];
#pragma unroll
    for (int mt = 0; mt < MT; ++mt)
#pragma unroll
      for (int nt = 0; nt < 4; ++nt)
        acc[mt][nt] = MFMA_B16(a[mt], bfr[nt], acc[mt][nt]);
  }

#pragma unroll
  for (int nt = 0; nt < 4; ++nt) {
    const int n = nb + wc + nt * 16 + l15;
    const float bv = bp[n];
#pragma unroll
    for (int mt = 0; mt < MT; ++mt)
#pragma unroll
      for (int r = 0; r < 4; ++r) {        // C/D: row=quad*4+r, col=l15
        const int m = m0 + wr + mt * 16 + quad * 4 + r;
        const float val = acc[mt][nt][r] + bv;
        if (OMODE == 2) {
          ((float*)o0)[(size_t)m * 1024 + n] = val;
        } else if (OMODE == 0) {
          ((u16*)o0)[(size_t)m * 1024 + n] = f2bf(val);
        } else {
          if (rg == 0)      ((u16*)o0)[(size_t)m * 1024 + n] = f2bf(val);
          else if (rg == 1) ((u16*)o1)[(size_t)m * 1024 + n] = f2bf(val);
          else {
            const int h = n >> 6, d = n & 63, bb = m >> 11, ss = m & 2047;
            ((u16*)o2)[((size_t)(bb * 16 + h) * 64 + d) * 2048 + ss] = f2bf(val);
          }
        }
      }
  }
}

// ---------------- fused attention v5: v4 + XCD-aware block remap -------------
// 4 waves x 32q, 128-key tiles. Flat wg id -> xcd = flat&7, slot = flat>>3;
// bh = xcd + 8*(slot>>4), qt = slot&15. All 16 q-tiles of a bh co-resident on
// one XCD (64 blocks/XCD = 2/CU x 32 CU) -> K/V L2-shared, fetched once.
__global__ __launch_bounds__(256) void attn_fused(
    const u16* Q, const u16* __restrict__ K,
    const u16* __restrict__ Vt, const int* __restrict__ mask,
    u16* ctx) {
  __shared__ __align__(16) u16 Ks[8 * 128 * 8];   // addr = dseg*1024 + ((key^(dseg&7))*8)
  __shared__ __align__(16) u16 Vs[16 * 64 * 8];   // addr = kseg*512  + ((d^(kseg&7))*8)
  __shared__ __align__(16) float Mf[128];         // current-tile bias 0/-inf
  const int t = threadIdx.x, wave = t >> 6, lane = t & 63;
  const int l31 = lane & 31, hi = lane >> 5;
  // XCD-aware remap (bijective over 512 blocks; dispatch round-robins flat id)
  const int lin = blockIdx.y * gridDim.x + blockIdx.x;
  const int xcd = lin & 7, slot = lin >> 3;
  const int bh = xcd + 8 * (slot >> 4);           // 4 bh per XCD
  const int qt = slot & 15;
  const int b = bh >> 4, h = bh & 15;
  const int q0w = qt * 128 + wave * 32;
  const float cs = 0.125f * 1.44269504f;          // 1/sqrt(dk) * log2(e)

  // Q B-frags (B[d][q]): lane holds Q[q=l31][d = kd*16 + hi*8 + j]
  const u16* Qp2 = Q + (size_t)(b * 2048 + q0w) * 1024 + h * 64;
  bf16x8 qb[4];
#pragma unroll
  for (int kd = 0; kd < 4; ++kd)
    qb[kd] = *(const bf16x8*)(Qp2 + (size_t)l31 * 1024 + kd * 16 + hi * 8);

  const u16* Kbase = K + (size_t)(b * 2048) * 1024 + h * 64;   // + key*1024
  const u16* Vbase = Vt + (size_t)bh * 64 * 2048;              // + d*2048 + key

  // staging maps (256 threads, 4 slots each for K and V)
  bf16x8 gk[4], gv[4];
#pragma unroll
  for (int s = 0; s < 4; ++s) {
    int slot2 = s * 256 + t;
    int kr = slot2 >> 3, ksg = slot2 & 7;
    gk[s] = *(const bf16x8*)&Kbase[(size_t)kr * 1024 + ksg * 8];
    int vr = slot2 >> 4, vsg = slot2 & 15;
    gv[s] = *(const bf16x8*)&Vbase[(size_t)vr * 2048 + vsg * 8];
  }
  int gmv = mask[b * 2048 + (t & 127)];

  bf16x8 onesb;                                   // bf16 1.0 x8 (ones B-frag)
#pragma unroll
  for (int j = 0; j < 8; ++j) onesb[j] = (short)0x3F80;

  const f32x16 sz = {0.f};
  f32x16 o0a = sz, o1a = sz;   // O[q-rows][d = ng*32 + l31], ng = 0,1
  f32x16 osum = sz;            // row-sums, same row indexing as o0a/o1a

  for (int kt = 0; kt < 2048; kt += 128) {
    __syncthreads();                              // prev tile fully consumed
#pragma unroll
    for (int s = 0; s < 4; ++s) {                 // waits prefetch vmcnt here
      int slot2 = s * 256 + t;
      int kr = slot2 >> 3, ksg = slot2 & 7;
      *(bf16x8*)&Ks[ksg * 1024 + ((kr ^ (ksg & 7)) * 8)] = gk[s];
      int vr = slot2 >> 4, vsg = slot2 & 15;
      *(bf16x8*)&Vs[vsg * 512 + ((vr ^ (vsg & 7)) * 8)] = gv[s];
    }
    if (t < 128) Mf[t] = gmv ? -__builtin_inff() : 0.f;
    __syncthreads();
    const int kn = (kt + 128) & 2047;             // wrap: in-bounds, unused on last
#pragma unroll
    for (int s = 0; s < 4; ++s) {
      int slot2 = s * 256 + t;
      int kr = slot2 >> 3, ksg = slot2 & 7;
      gk[s] = *(const bf16x8*)&Kbase[(size_t)(kn + kr) * 1024 + ksg * 8];
      int vr = slot2 >> 4, vsg = slot2 & 15;
      gv[s] = *(const bf16x8*)&Vbase[(size_t)vr * 2048 + kn + vsg * 8];
    }
    gmv = mask[b * 2048 + kn + (t & 127)];

#pragma unroll
    for (int kg = 0; kg < 4; ++kg) {              // 4 groups of 32 keys
      // S[key][q]: A = K rows (key = kg*32 + l31, d-slice kd), B = Q
      f32x16 S = sz;
#pragma unroll
      for (int kd = 0; kd < 4; ++kd) {
        const int dseg = kd * 2 + hi;
        const bf16x8 kf = *(const bf16x8*)
            &Ks[dseg * 1024 + (((kg * 32 + l31) ^ (dseg & 7)) * 8)];
        S = MFMA32_B16(kf, qb[kd], S);
      }
      // softmax piece: p = exp2(fma(s,cs,bias)); bias broadcast from LDS
      u32 W[8];
#pragma unroll
      for (int c = 0; c < 4; ++c) {
        const float4 bias4 = *(const float4*)&Mf[kg * 32 + c * 8 + hi * 4];
        const float p0 = exp2f(fmaf(S[c * 4 + 0], cs, bias4.x));
        const float p1 = exp2f(fmaf(S[c * 4 + 1], cs, bias4.y));
        const float p2 = exp2f(fmaf(S[c * 4 + 2], cs, bias4.z));
        const float p3 = exp2f(fmaf(S[c * 4 + 3], cs, bias4.w));
        W[2 * c + 0] = cvtpk(p0, p1);
        W[2 * c + 1] = cvtpk(p2, p3);
      }
      // PA frags: keys become lane-contiguous via permlane32_swap
      {
        i32x2 r0 = __builtin_amdgcn_permlane32_swap((int)W[0], (int)W[2], false, false);
        i32x2 r1 = __builtin_amdgcn_permlane32_swap((int)W[1], (int)W[3], false, false);
        i32x2 r2 = __builtin_amdgcn_permlane32_swap((int)W[4], (int)W[6], false, false);
        i32x2 r3 = __builtin_amdgcn_permlane32_swap((int)W[5], (int)W[7], false, false);
        union { bf16x8 v; u32 w[4]; } pa0, pa1;
        pa0.w[0] = (u32)r0[0]; pa0.w[1] = (u32)r1[0];
        pa0.w[2] = (u32)r0[1]; pa0.w[3] = (u32)r1[1];
        pa1.w[0] = (u32)r2[0]; pa1.w[1] = (u32)r3[0];
        pa1.w[2] = (u32)r2[1]; pa1.w[3] = (u32)r3[1];
        // O += P @ V; osum += P @ ones (row-sum, same C layout)
#pragma unroll
        for (int ks2 = 0; ks2 < 2; ++ks2) {
          const bf16x8 pav = ks2 ? pa1.v : pa0.v;
          const int kseg = (kg * 2 + ks2) * 2 + hi;
          const bf16x8 vf0 = *(const bf16x8*)
              &Vs[kseg * 512 + ((l31 ^ (kseg & 7)) * 8)];
          const bf16x8 vf1 = *(const bf16x8*)
              &Vs[kseg * 512 + (((32 + l31) ^ (kseg & 7)) * 8)];
          o0a = MFMA32_B16(pav, vf0, o0a);
          o1a = MFMA32_B16(pav, vf1, o1a);
          osum = MFMA32_B16(pav, onesb, osum);
        }
      }
    }
  }
  // normalize: osum rows == o rows (q = 8c+4hi+j), elementwise
  u16* cp = ctx + (size_t)(b * 2048 + q0w) * 1024 + h * 64;
#pragma unroll
  for (int c = 0; c < 4; ++c) {
#pragma unroll
    for (int j = 0; j < 4; ++j) {
      const int e = c * 4 + j;
      const int row = 8 * c + 4 * hi + j;
      const float iv = osum[e] > 0.f ? 1.f / osum[e] : 0.f;
      cp[(size_t)row * 1024 + l31]      = f2bf(o0a[e] * iv);
      cp[(size_t)row * 1024 + 32 + l31] = f2bf(o1a[e] * iv);
    }
  }
}

// ---------------- host launch ------------------------------------------------
extern "C" void kernel_launch(void* const* d_in, const int* in_sizes, int n_in,
                              void* d_out, int out_size, void* d_ws, size_t ws_size,
                              hipStream_t stream) {
  const float* q    = (const float*)d_in[0];
  const float* k    = (const float*)d_in[1];
  const float* v    = (const float*)d_in[2];
  const int*   mask = (const int*)d_in[3];
  const float* Wq = (const float*)d_in[4];  const float* bq = (const float*)d_in[5];
  const float* Wk = (const float*)d_in[6];  const float* bk = (const float*)d_in[7];
  const float* Wv = (const float*)d_in[8];  const float* bv = (const float*)d_in[9];
  const float* Wo = (const float*)d_in[10]; const float* bo = (const float*)d_in[11];

  char* ws = (char*)d_ws;                       // 16 MB
  u16*   Kp  = (u16*)(ws + ((size_t)0 << 20));  // [4096][1024] bf16
  u16*   Vt  = (u16*)(ws + ((size_t)8 << 20));  // [32][64][2048] bf16
  float* O32 = (float*)ws;                      // [4096][1024] fp32 (after attn)

  char* od = (char*)d_out;                      // 16 MB
  u16* ctx = (u16*)od;                          // [0,8MB): Qp then ctx in-place
  u16* WqT = (u16*)(od + ((size_t)8 << 20));
  u16* WkT = (u16*)(od + ((size_t)10 << 20));
  u16* WvT = (u16*)(od + ((size_t)12 << 20));
  u16* WoT = (u16*)(od + ((size_t)14 << 20));

  dim3 blk(256);
  prep_w<<<dim3(16, 16, 4), blk, 0, stream>>>(Wq, Wk, Wv, Wo, WqT, WkT, WvT, WoT);
  gemm_bias<4, 1, 3><<<dim3(32, 24), blk, 0, stream>>>(
      q, k, v, WqT, bq, bk, bv, (void*)ctx, (void*)Kp, (void*)Vt);
  attn_fused<<<dim3(16, 32), dim3(256), 0, stream>>>(ctx, Kp, Vt, mask, ctx);
  gemm_bias<2, 0, 2><<<dim3(64, 8), blk, 0, stream>>>(
      ctx, nullptr, nullptr, WoT, bo, nullptr, nullptr, (void*)O32, nullptr, nullptr);
  hipMemcpyAsync(d_out, O32, (size_t)out_size * sizeof(float),
                 hipMemcpyDeviceToDevice, stream);
}

// Round 10
// 259.004 us; speedup vs baseline: 1.0169x; 1.0169x over previous
//
#include <hip/hip_runtime.h>

// MHA: fp32 in, fp32 out. B=2, S=2048, D=1024, H=16, dk=64. bf16 MFMA internals.
// ws 16MB: Kp[0,8) Vt[8,16) -> later O32[0,16).
// d_out 16MB: Qp/ctx[0,8), WqT/WkT/WvT/WoT bf16 [8,16).
// GEMM: round-0 structure + LDS seg-XOR swizzle (seg ^= (row>>1)&3 both sides).
//       [row][32] layout has 64B row stride = 16 banks -> 8-way conflict on
//       every b128 frag read/staging write (measured 3.1M conflict cycles);
//       swizzle makes it 2-way (free, m136).
// attn v5 (kept): 4 waves x 32q x 128-key tiles, 32x32 MFMA, swapped QK^T,
//       in-register P via cvt_pk+permlane32_swap, mask as f32 bias in LDS,
//       row-sums via MFMA(P, ones), XOR LDS (0 conflicts), XCD-aware remap
//       (FETCH 73.9 -> 12.4 MB; duration-neutral but frees HBM).

typedef unsigned short u16;
typedef unsigned int u32;
typedef __attribute__((ext_vector_type(8))) short bf16x8;    // MFMA A/B frag (4 VGPR)
typedef __attribute__((ext_vector_type(4))) float f32x4;     // 16x16 C/D frag
typedef __attribute__((ext_vector_type(16))) float f32x16;   // 32x32 C/D frag
typedef __attribute__((ext_vector_type(2))) int i32x2;

static __device__ __forceinline__ u16 f2bf(float x) {        // round-half-up
  union { float f; u32 i; } v; v.f = x;
  return (u16)((v.i + 0x8000u) >> 16);
}

static __device__ __forceinline__ u32 cvtpk(float lo, float hi) {
  u32 r;
  asm("v_cvt_pk_bf16_f32 %0, %1, %2" : "=v"(r) : "v"(lo), "v"(hi));
  return r;
}

#define MFMA_B16(a, b, c) __builtin_amdgcn_mfma_f32_16x16x32_bf16((a), (b), (c), 0, 0, 0)
#define MFMA32_B16(a, b, c) __builtin_amdgcn_mfma_f32_32x32x16_bf16((a), (b), (c), 0, 0, 0)

// ---------------- prep: W fp32[K][N] -> Wt bf16[N][K], 4 weights -------------
__global__ __launch_bounds__(256) void prep_w(
    const float* __restrict__ w0, const float* __restrict__ w1,
    const float* __restrict__ w2, const float* __restrict__ w3,
    u16* __restrict__ t0, u16* __restrict__ t1,
    u16* __restrict__ t2, u16* __restrict__ t3) {
  __shared__ u16 tile[64 * 68];
  const float* W; u16* T;
  switch (blockIdx.z) {
    case 0: W = w0; T = t0; break;
    case 1: W = w1; T = t1; break;
    case 2: W = w2; T = t2; break;
    default: W = w3; T = t3; break;
  }
  const int t = threadIdx.x;
  const int k0 = blockIdx.x * 64, n0 = blockIdx.y * 64;
#pragma unroll
  for (int it = 0; it < 4; ++it) {
    int idx = it * 256 + t;
    int r = idx >> 4, c4 = idx & 15;
    float4 v = *(const float4*)&W[(size_t)(k0 + r) * 1024 + n0 + c4 * 4];
    tile[r * 68 + c4 * 4 + 0] = f2bf(v.x);
    tile[r * 68 + c4 * 4 + 1] = f2bf(v.y);
    tile[r * 68 + c4 * 4 + 2] = f2bf(v.z);
    tile[r * 68 + c4 * 4 + 3] = f2bf(v.w);
  }
  __syncthreads();
#pragma unroll
  for (int it = 0; it < 2; ++it) {
    int idx = it * 256 + t;
    int n = idx >> 3, kc = idx & 7;
    bf16x8 pk;
#pragma unroll
    for (int j = 0; j < 8; ++j) pk[j] = (short)tile[(kc * 8 + j) * 68 + n];
    *(bf16x8*)&T[(size_t)(n0 + n) * 1024 + k0 + kc * 8] = pk;
  }
}

// ---------------- GEMM, tile (MT*32)x128, BK=32, reg-staged prefetch ---------
// LDS seg swizzle: element [row][seg*8..] stored at seg_phys = seg^((row>>1)&3).
template <int MT, int AMODE, int OMODE>
__global__ __launch_bounds__(256) void gemm_bias(
    const void* a0v, const void* a1v, const void* a2v,
    const u16* __restrict__ Wt,
    const float* b0, const float* b1, const float* b2,
    void* o0, void* o1, void* o2) {
  __shared__ __align__(16) u16 As[MT * 32 * 32];
  __shared__ __align__(16) u16 Bs[128 * 32];
  const int t = threadIdx.x, wave = t >> 6, lane = t & 63;
  const int l15 = lane & 15, quad = lane >> 4;
  const int m0 = blockIdx.x * (MT * 32);
  const int n0 = blockIdx.y * 128;
  const int rg = (OMODE == 3) ? (n0 >> 10) : 0;
  const void* Av = (rg == 0) ? a0v : (rg == 1 ? a1v : a2v);
  const float* bp = (rg == 0) ? b0 : (rg == 1 ? b1 : b2);
  const int nb = (OMODE == 3) ? (n0 & 1023) : n0;
  const int wr = (wave >> 1) * (MT * 16), wc = (wave & 1) * 64;

  const f32x4 fz = {0.f, 0.f, 0.f, 0.f};
  f32x4 acc[MT][4];
#pragma unroll
  for (int mt = 0; mt < MT; ++mt)
#pragma unroll
    for (int nt = 0; nt < 4; ++nt) acc[mt][nt] = fz;

  float4 pa[MT / 2][2]; bf16x8 pab[MT / 2]; bf16x8 pb[2];
#pragma unroll
  for (int s = 0; s < MT / 2; ++s) {
    int idx = s * 256 + t, row = idx >> 2, seg = idx & 3;
    if (AMODE == 1) {
      const float* ap = (const float*)Av + (size_t)(m0 + row) * 1024 + seg * 8;
      pa[s][0] = *(const float4*)ap; pa[s][1] = *(const float4*)(ap + 4);
    } else {
      pab[s] = *(const bf16x8*)((const u16*)Av + (size_t)(m0 + row) * 1024 + seg * 8);
    }
  }
#pragma unroll
  for (int s = 0; s < 2; ++s) {
    int idx = s * 256 + t, row = idx >> 2, seg = idx & 3;
    pb[s] = *(const bf16x8*)&Wt[(size_t)(n0 + row) * 1024 + seg * 8];
  }

  for (int kb = 0; kb < 1024; kb += 32) {
    __syncthreads();
#pragma unroll
    for (int s = 0; s < MT / 2; ++s) {
      int idx = s * 256 + t, row = idx >> 2, seg = idx & 3;
      bf16x8 pk;
      if (AMODE == 1) {
        pk[0] = (short)f2bf(pa[s][0].x); pk[1] = (short)f2bf(pa[s][0].y);
        pk[2] = (short)f2bf(pa[s][0].z); pk[3] = (short)f2bf(pa[s][0].w);
        pk[4] = (short)f2bf(pa[s][1].x); pk[5] = (short)f2bf(pa[s][1].y);
        pk[6] = (short)f2bf(pa[s][1].z); pk[7] = (short)f2bf(pa[s][1].w);
      } else pk = pab[s];
      *(bf16x8*)&As[row * 32 + ((seg ^ ((row >> 1) & 3)) * 8)] = pk;
    }
#pragma unroll
    for (int s = 0; s < 2; ++s) {
      int idx = s * 256 + t, row = idx >> 2, seg = idx & 3;
      *(bf16x8*)&Bs[row * 32 + ((seg ^ ((row >> 1) & 3)) * 8)] = pb[s];
    }
    __syncthreads();
    const int kn = (kb + 32) & 1023;
#pragma unroll
    for (int s = 0; s < MT / 2; ++s) {
      int idx = s * 256 + t, row = idx >> 2, seg = idx & 3;
      if (AMODE == 1) {
        const float* ap = (const float*)Av + (size_t)(m0 + row) * 1024 + kn + seg * 8;
        pa[s][0] = *(const float4*)ap; pa[s][1] = *(const float4*)(ap + 4);
      } else {
        pab[s] = *(const bf16x8*)((const u16*)Av + (size_t)(m0 + row) * 1024 + kn + seg * 8);
      }
    }
#pragma unroll
    for (int s = 0; s < 2; ++s) {
      int idx = s * 256 + t, row = idx >> 2, seg = idx & 3;
      pb[s] = *(const bf16x8*)&Wt[(size_t)(n0 + row) * 1024 + kn + seg * 8];
    }
    bf16x8 a[MT], bfr[4];
#pragma unroll
    for (int mt = 0; mt < MT; ++mt) {
      const int ra = wr + mt * 16 + l15;
      a[mt] = *(const bf16x8*)&As[ra * 32 + ((quad ^ ((ra >> 1) & 3)) * 8)];
    }
#pragma unroll
    for (int nt = 0; nt < 4; ++nt) {
      const int rb = wc + nt * 16 + l15;
      bfr[nt] = *(const bf16x8*)&Bs[rb * 32 + ((quad ^ ((rb >> 1) & 3)) * 8)];
    }
#pragma unroll
    for (int mt = 0; mt < MT; ++mt)
#pragma unroll
      for (int nt = 0; nt < 4; ++nt)
        acc[mt][nt] = MFMA_B16(a[mt], bfr[nt], acc[mt][nt]);
  }

#pragma unroll
  for (int nt = 0; nt < 4; ++nt) {
    const int n = nb + wc + nt * 16 + l15;
    const float bv = bp[n];
#pragma unroll
    for (int mt = 0; mt < MT; ++mt)
#pragma unroll
      for (int r = 0; r < 4; ++r) {        // C/D: row=quad*4+r, col=l15
        const int m = m0 + wr + mt * 16 + quad * 4 + r;
        const float val = acc[mt][nt][r] + bv;
        if (OMODE == 2) {
          ((float*)o0)[(size_t)m * 1024 + n] = val;
        } else if (OMODE == 0) {
          ((u16*)o0)[(size_t)m * 1024 + n] = f2bf(val);
        } else {
          if (rg == 0)      ((u16*)o0)[(size_t)m * 1024 + n] = f2bf(val);
          else if (rg == 1) ((u16*)o1)[(size_t)m * 1024 + n] = f2bf(val);
          else {
            const int h = n >> 6, d = n & 63, bb = m >> 11, ss = m & 2047;
            ((u16*)o2)[((size_t)(bb * 16 + h) * 64 + d) * 2048 + ss] = f2bf(val);
          }
        }
      }
  }
}

// ---------------- fused attention v5: v4 + XCD-aware block remap -------------
__global__ __launch_bounds__(256) void attn_fused(
    const u16* Q, const u16* __restrict__ K,
    const u16* __restrict__ Vt, const int* __restrict__ mask,
    u16* ctx) {
  __shared__ __align__(16) u16 Ks[8 * 128 * 8];   // addr = dseg*1024 + ((key^(dseg&7))*8)
  __shared__ __align__(16) u16 Vs[16 * 64 * 8];   // addr = kseg*512  + ((d^(kseg&7))*8)
  __shared__ __align__(16) float Mf[128];         // current-tile bias 0/-inf
  const int t = threadIdx.x, wave = t >> 6, lane = t & 63;
  const int l31 = lane & 31, hi = lane >> 5;
  // XCD-aware remap (bijective over 512 blocks; dispatch round-robins flat id)
  const int lin = blockIdx.y * gridDim.x + blockIdx.x;
  const int xcd = lin & 7, slot = lin >> 3;
  const int bh = xcd + 8 * (slot >> 4);           // 4 bh per XCD
  const int qt = slot & 15;
  const int b = bh >> 4, h = bh & 15;
  const int q0w = qt * 128 + wave * 32;
  const float cs = 0.125f * 1.44269504f;          // 1/sqrt(dk) * log2(e)

  // Q B-frags (B[d][q]): lane holds Q[q=l31][d = kd*16 + hi*8 + j]
  const u16* Qp2 = Q + (size_t)(b * 2048 + q0w) * 1024 + h * 64;
  bf16x8 qb[4];
#pragma unroll
  for (int kd = 0; kd < 4; ++kd)
    qb[kd] = *(const bf16x8*)(Qp2 + (size_t)l31 * 1024 + kd * 16 + hi * 8);

  const u16* Kbase = K + (size_t)(b * 2048) * 1024 + h * 64;   // + key*1024
  const u16* Vbase = Vt + (size_t)bh * 64 * 2048;              // + d*2048 + key

  // staging maps (256 threads, 4 slots each for K and V)
  bf16x8 gk[4], gv[4];
#pragma unroll
  for (int s = 0; s < 4; ++s) {
    int slot2 = s * 256 + t;
    int kr = slot2 >> 3, ksg = slot2 & 7;
    gk[s] = *(const bf16x8*)&Kbase[(size_t)kr * 1024 + ksg * 8];
    int vr = slot2 >> 4, vsg = slot2 & 15;
    gv[s] = *(const bf16x8*)&Vbase[(size_t)vr * 2048 + vsg * 8];
  }
  int gmv = mask[b * 2048 + (t & 127)];

  bf16x8 onesb;                                   // bf16 1.0 x8 (ones B-frag)
#pragma unroll
  for (int j = 0; j < 8; ++j) onesb[j] = (short)0x3F80;

  const f32x16 sz = {0.f};
  f32x16 o0a = sz, o1a = sz;   // O[q-rows][d = ng*32 + l31], ng = 0,1
  f32x16 osum = sz;            // row-sums, same row indexing as o0a/o1a

  for (int kt = 0; kt < 2048; kt += 128) {
    __syncthreads();                              // prev tile fully consumed
#pragma unroll
    for (int s = 0; s < 4; ++s) {                 // waits prefetch vmcnt here
      int slot2 = s * 256 + t;
      int kr = slot2 >> 3, ksg = slot2 & 7;
      *(bf16x8*)&Ks[ksg * 1024 + ((kr ^ (ksg & 7)) * 8)] = gk[s];
      int vr = slot2 >> 4, vsg = slot2 & 15;
      *(bf16x8*)&Vs[vsg * 512 + ((vr ^ (vsg & 7)) * 8)] = gv[s];
    }
    if (t < 128) Mf[t] = gmv ? -__builtin_inff() : 0.f;
    __syncthreads();
    const int kn = (kt + 128) & 2047;             // wrap: in-bounds, unused on last
#pragma unroll
    for (int s = 0; s < 4; ++s) {
      int slot2 = s * 256 + t;
      int kr = slot2 >> 3, ksg = slot2 & 7;
      gk[s] = *(const bf16x8*)&Kbase[(size_t)(kn + kr) * 1024 + ksg * 8];
      int vr = slot2 >> 4, vsg = slot2 & 15;
      gv[s] = *(const bf16x8*)&Vbase[(size_t)vr * 2048 + kn + vsg * 8];
    }
    gmv = mask[b * 2048 + kn + (t & 127)];

#pragma unroll
    for (int kg = 0; kg < 4; ++kg) {              // 4 groups of 32 keys
      // S[key][q]: A = K rows (key = kg*32 + l31, d-slice kd), B = Q
      f32x16 S = sz;
#pragma unroll
      for (int kd = 0; kd < 4; ++kd) {
        const int dseg = kd * 2 + hi;
        const bf16x8 kf = *(const bf16x8*)
            &Ks[dseg * 1024 + (((kg * 32 + l31) ^ (dseg & 7)) * 8)];
        S = MFMA32_B16(kf, qb[kd], S);
      }
      // softmax piece: p = exp2(fma(s,cs,bias)); bias broadcast from LDS
      u32 W[8];
#pragma unroll
      for (int c = 0; c < 4; ++c) {
        const float4 bias4 = *(const float4*)&Mf[kg * 32 + c * 8 + hi * 4];
        const float p0 = exp2f(fmaf(S[c * 4 + 0], cs, bias4.x));
        const float p1 = exp2f(fmaf(S[c * 4 + 1], cs, bias4.y));
        const float p2 = exp2f(fmaf(S[c * 4 + 2], cs, bias4.z));
        const float p3 = exp2f(fmaf(S[c * 4 + 3], cs, bias4.w));
        W[2 * c + 0] = cvtpk(p0, p1);
        W[2 * c + 1] = cvtpk(p2, p3);
      }
      // PA frags: keys become lane-contiguous via permlane32_swap
      {
        i32x2 r0 = __builtin_amdgcn_permlane32_swap((int)W[0], (int)W[2], false, false);
        i32x2 r1 = __builtin_amdgcn_permlane32_swap((int)W[1], (int)W[3], false, false);
        i32x2 r2 = __builtin_amdgcn_permlane32_swap((int)W[4], (int)W[6], false, false);
        i32x2 r3 = __builtin_amdgcn_permlane32_swap((int)W[5], (int)W[7], false, false);
        union { bf16x8 v; u32 w[4]; } pa0, pa1;
        pa0.w[0] = (u32)r0[0]; pa0.w[1] = (u32)r1[0];
        pa0.w[2] = (u32)r0[1]; pa0.w[3] = (u32)r1[1];
        pa1.w[0] = (u32)r2[0]; pa1.w[1] = (u32)r3[0];
        pa1.w[2] = (u32)r2[1]; pa1.w[3] = (u32)r3[1];
        // O += P @ V; osum += P @ ones (row-sum, same C layout)
#pragma unroll
        for (int ks2 = 0; ks2 < 2; ++ks2) {
          const bf16x8 pav = ks2 ? pa1.v : pa0.v;
          const int kseg = (kg * 2 + ks2) * 2 + hi;
          const bf16x8 vf0 = *(const bf16x8*)
              &Vs[kseg * 512 + ((l31 ^ (kseg & 7)) * 8)];
          const bf16x8 vf1 = *(const bf16x8*)
              &Vs[kseg * 512 + (((32 + l31) ^ (kseg & 7)) * 8)];
          o0a = MFMA32_B16(pav, vf0, o0a);
          o1a = MFMA32_B16(pav, vf1, o1a);
          osum = MFMA32_B16(pav, onesb, osum);
        }
      }
    }
  }
  // normalize: osum rows == o rows (q = 8c+4hi+j), elementwise
  u16* cp = ctx + (size_t)(b * 2048 + q0w) * 1024 + h * 64;
#pragma unroll
  for (int c = 0; c < 4; ++c) {
#pragma unroll
    for (int j = 0; j < 4; ++j) {
      const int e = c * 4 + j;
      const int row = 8 * c + 4 * hi + j;
      const float iv = osum[e] > 0.f ? 1.f / osum[e] : 0.f;
      cp[(size_t)row * 1024 + l31]      = f2bf(o0a[e] * iv);
      cp[(size_t)row * 1024 + 32 + l31] = f2bf(o1a[e] * iv);
    }
  }
}

// ---------------- host launch ------------------------------------------------
extern "C" void kernel_launch(void* const* d_in, const int* in_sizes, int n_in,
                              void* d_out, int out_size, void* d_ws, size_t ws_size,
                              hipStream_t stream) {
  const float* q    = (const float*)d_in[0];
  const float* k    = (const float*)d_in[1];
  const float* v    = (const float*)d_in[2];
  const int*   mask = (const int*)d_in[3];
  const float* Wq = (const float*)d_in[4];  const float* bq = (const float*)d_in[5];
  const float* Wk = (const float*)d_in[6];  const float* bk = (const float*)d_in[7];
  const float* Wv = (const float*)d_in[8];  const float* bv = (const float*)d_in[9];
  const float* Wo = (const float*)d_in[10]; const float* bo = (const float*)d_in[11];

  char* ws = (char*)d_ws;                       // 16 MB
  u16*   Kp  = (u16*)(ws + ((size_t)0 << 20));  // [4096][1024] bf16
  u16*   Vt  = (u16*)(ws + ((size_t)8 << 20));  // [32][64][2048] bf16
  float* O32 = (float*)ws;                      // [4096][1024] fp32 (after attn)

  char* od = (char*)d_out;                      // 16 MB
  u16* ctx = (u16*)od;                          // [0,8MB): Qp then ctx in-place
  u16* WqT = (u16*)(od + ((size_t)8 << 20));
  u16* WkT = (u16*)(od + ((size_t)10 << 20));
  u16* WvT = (u16*)(od + ((size_t)12 << 20));
  u16* WoT = (u16*)(od + ((size_t)14 << 20));

  dim3 blk(256);
  prep_w<<<dim3(16, 16, 4), blk, 0, stream>>>(Wq, Wk, Wv, Wo, WqT, WkT, WvT, WoT);
  gemm_bias<4, 1, 3><<<dim3(32, 24), blk, 0, stream>>>(
      q, k, v, WqT, bq, bk, bv, (void*)ctx, (void*)Kp, (void*)Vt);
  attn_fused<<<dim3(16, 32), dim3(256), 0, stream>>>(ctx, Kp, Vt, mask, ctx);
  gemm_bias<2, 0, 2><<<dim3(64, 8), blk, 0, stream>>>(
      ctx, nullptr, nullptr, WoT, bo, nullptr, nullptr, (void*)O32, nullptr, nullptr);
  hipMemcpyAsync(d_out, O32, (size_t)out_size * sizeof(float),
                 hipMemcpyDeviceToDevice, stream);
}